// Round 4
// baseline (280.688 us; speedup 1.0000x reference)
//
#include <hip/hip_runtime.h>

#define BATCH 16384

typedef float f4 __attribute__((ext_vector_type(4)));

// One block per segment b. 192 threads = 3 waves:
//   wave 0 : out0[b][0:64]   = sum_j table0[idx0[j]][:] * w0[j]   (weighted sum)
//   wave 1 : out1[b][0:64]   = mean_j table1[idx1[j]][0:64]
//   wave 2 : out1[b][64:128] = mean_j table1[idx1[j]][64:128]
// Within a wave: 4 row-groups x 16 lanes; lane gl loads float4 at col gl*4
// (16 lanes x 16B = 64 floats = the wave's row-chunk). Main loop processes
// 64 rows per chunk: idx/w for the whole chunk are fetched with ONE coalesced
// lane-parallel load each, broadcast via __shfl (bpermute - no VMEM slot, no
// dependent idx->gather chain), then each group issues 8 independent f4 row
// gathers at a time (32 rows in flight per wave). Round-2 profile was
// latency-bound (HBM 34%, VALU 13%): this doubles gather MLP and removes the
// redundant per-lane idx/w VMEM traffic (half of all VMEM instructions).
__global__ __launch_bounds__(192)
void combine_jagged_kernel(const float* __restrict__ table0,
                           const float* __restrict__ table1,
                           const float* __restrict__ w0,
                           const int* __restrict__ idx0,
                           const int* __restrict__ idx1,
                           const int* __restrict__ off0,
                           const int* __restrict__ off1,
                           float* __restrict__ out) {
    const int b    = blockIdx.x;
    const int wave = threadIdx.x >> 6;   // 0,1,2
    const int lane = threadIdx.x & 63;
    const int grp  = lane >> 4;          // row-group 0..3
    const int gl   = lane & 15;          // lane within group

    const float* tab; const int* idx; const int* off; const float* wp;
    int ld, colbase;
    if (wave == 0)      { tab = table0; idx = idx0; off = off0; wp = w0;      ld = 64;  colbase = 0;  }
    else if (wave == 1) { tab = table1; idx = idx1; off = off1; wp = nullptr; ld = 128; colbase = 0;  }
    else                { tab = table1; idx = idx1; off = off1; wp = nullptr; ld = 128; colbase = 64; }

    const int s = off[b];
    const int e = off[b + 1];
    const int col = colbase + gl * 4;

    f4 acc = {0.0f, 0.0f, 0.0f, 0.0f};

    int jc = s;
    // main loop: 64 rows per chunk
    for (; jc + 64 <= e; jc += 64) {
        const int   myidx = idx[jc + lane];                 // 1 coalesced load
        const float myw   = wp ? wp[jc + lane] : 1.0f;      // 1 coalesced load

        #pragma unroll
        for (int k0 = 0; k0 < 16; k0 += 8) {
            int   r[8];
            float a[8];
            #pragma unroll
            for (int k = 0; k < 8; ++k) {
                const int src = grp + 4 * (k0 + k);         // row jc+src for this group
                r[k] = __shfl(myidx, src, 64);
                a[k] = wp ? __shfl(myw, src, 64) : 1.0f;
            }
            f4 v[8];
            #pragma unroll
            for (int k = 0; k < 8; ++k)
                v[k] = *(const f4*)(tab + (size_t)r[k] * ld + col);
            #pragma unroll
            for (int k = 0; k < 8; ++k)
                acc += v[k] * a[k];
        }
    }
    // tail: one row at a time per group (rows jc+grp, jc+grp+4, ...)
    for (int j = jc + grp; j < e; j += 4) {
        const int   r = idx[j];
        const float a = wp ? wp[j] : 1.0f;
        const f4 v = *(const f4*)(tab + (size_t)r * ld + col);
        acc += v * a;
    }

    // reduce across the 4 row-groups: lanes l, l^16, l^32, l^48 hold the same col
    acc.x += __shfl_xor(acc.x, 16, 64);
    acc.y += __shfl_xor(acc.y, 16, 64);
    acc.z += __shfl_xor(acc.z, 16, 64);
    acc.w += __shfl_xor(acc.w, 16, 64);
    acc.x += __shfl_xor(acc.x, 32, 64);
    acc.y += __shfl_xor(acc.y, 32, 64);
    acc.z += __shfl_xor(acc.z, 32, 64);
    acc.w += __shfl_xor(acc.w, 32, 64);

    if (grp == 0) {
        if (wave == 0) {
            *(f4*)(out + (size_t)b * 64 + col) = acc;   // empty segment -> 0
        } else {
            const int cnt = e - s;
            const float inv = (cnt > 0) ? 1.0f / (float)cnt : 0.0f;  // mean; empty -> 0
            acc *= inv;
            *(f4*)(out + (size_t)BATCH * 64 + (size_t)b * 128 + col) = acc;
        }
    }
}

extern "C" void kernel_launch(void* const* d_in, const int* in_sizes, int n_in,
                              void* d_out, int out_size, void* d_ws, size_t ws_size,
                              hipStream_t stream) {
    const float* table0 = (const float*)d_in[0];   // [V, 64]
    const float* table1 = (const float*)d_in[1];   // [V, 128]
    const float* w0     = (const float*)d_in[2];   // [T]
    const int*   idx0   = (const int*)d_in[3];     // [T]
    const int*   idx1   = (const int*)d_in[4];     // [T]
    const int*   off0   = (const int*)d_in[5];     // [B+1]
    const int*   off1   = (const int*)d_in[6];     // [B+1]
    float* out = (float*)d_out;                    // [B*64] ++ [B*128]

    combine_jagged_kernel<<<BATCH, 192, 0, stream>>>(
        table0, table1, w0, idx0, idx1, off0, off1, out);
}

// Round 5
// 272.083 us; speedup vs baseline: 1.0316x; 1.0316x over previous
//
#include <hip/hip_runtime.h>

#define BATCH 16384

// One block per segment b. 192 threads = 3 waves:
//   wave 0 : out0[b][0:64]   = sum_j table0[idx0[j]][:] * w0[j]   (weighted sum)
//   wave 1 : out1[b][0:64]   = mean_j table1[idx1[j]][0:64]
//   wave 2 : out1[b][64:128] = mean_j table1[idx1[j]][64:128]
//
// Key change vs round-4 (which regressed: shfl broadcast put ds_bpermute+lgkmcnt
// on the gather critical path): iterate ONE row per wave-step so idx[j]/w0[j]
// addresses are wave-uniform -> compiler scalarizes them to s_load (SMEM pipe).
// The ONLY VMEM instructions in the loop are the payload row-gathers
// (global_load_dword, 64 lanes x 4B = 256B/instr), unrolled 8-deep ->
// 8 independent gathers in flight per wave, ~30 waves/CU, and the vmcnt queue
// carries payload only. Weights multiply as SGPR operands to v_fmac.
__global__ __launch_bounds__(192)
void combine_jagged_kernel(const float* __restrict__ table0,
                           const float* __restrict__ table1,
                           const float* __restrict__ w0,
                           const int* __restrict__ idx0,
                           const int* __restrict__ idx1,
                           const int* __restrict__ off0,
                           const int* __restrict__ off1,
                           float* __restrict__ out) {
    const int b    = blockIdx.x;
    const int wave = threadIdx.x >> 6;   // 0,1,2
    const int lane = threadIdx.x & 63;

    if (wave == 0) {
        // feature 0: weighted sum, row = 64 floats, lane owns col=lane
        const int s = __builtin_amdgcn_readfirstlane(off0[b]);
        const int e = __builtin_amdgcn_readfirstlane(off0[b + 1]);
        const float* tab = table0 + lane;
        float acc = 0.0f;
        int j = s;
        for (; j + 8 <= e; j += 8) {
            float v[8];
            #pragma unroll
            for (int k = 0; k < 8; ++k) {
                const int r = idx0[j + k];               // uniform addr -> s_load
                v[k] = tab[(size_t)r * 64];              // payload gather
            }
            #pragma unroll
            for (int k = 0; k < 8; ++k) {
                acc = fmaf(v[k], w0[j + k], acc);        // w0: s_load, SGPR operand
            }
        }
        for (; j < e; ++j) {
            const int r = idx0[j];
            acc = fmaf(tab[(size_t)r * 64], w0[j], acc);
        }
        out[(size_t)b * 64 + lane] = acc;                // empty segment -> 0
    } else {
        // feature 1: mean, row = 128 floats; wave1 cols 0..63, wave2 cols 64..127
        const int s = __builtin_amdgcn_readfirstlane(off1[b]);
        const int e = __builtin_amdgcn_readfirstlane(off1[b + 1]);
        const int colbase = (wave - 1) * 64;
        const float* tab = table1 + colbase + lane;
        float acc = 0.0f;
        int j = s;
        for (; j + 8 <= e; j += 8) {
            float v[8];
            #pragma unroll
            for (int k = 0; k < 8; ++k) {
                const int r = idx1[j + k];               // uniform addr -> s_load
                v[k] = tab[(size_t)r * 128];             // payload gather
            }
            #pragma unroll
            for (int k = 0; k < 8; ++k) {
                acc += v[k];
            }
        }
        for (; j < e; ++j) {
            const int r = idx1[j];
            acc += tab[(size_t)r * 128];
        }
        const int cnt = e - s;
        const float inv = (cnt > 0) ? 1.0f / (float)cnt : 0.0f;   // mean; empty -> 0
        out[(size_t)BATCH * 64 + (size_t)b * 128 + colbase + lane] = acc * inv;
    }
}

extern "C" void kernel_launch(void* const* d_in, const int* in_sizes, int n_in,
                              void* d_out, int out_size, void* d_ws, size_t ws_size,
                              hipStream_t stream) {
    const float* table0 = (const float*)d_in[0];   // [V, 64]
    const float* table1 = (const float*)d_in[1];   // [V, 128]
    const float* w0     = (const float*)d_in[2];   // [T]
    const int*   idx0   = (const int*)d_in[3];     // [T]
    const int*   idx1   = (const int*)d_in[4];     // [T]
    const int*   off0   = (const int*)d_in[5];     // [B+1]
    const int*   off1   = (const int*)d_in[6];     // [B+1]
    float* out = (float*)d_out;                    // [B*64] ++ [B*128]

    combine_jagged_kernel<<<BATCH, 192, 0, stream>>>(
        table0, table1, w0, idx0, idx1, off0, off1, out);
}

// Round 9
// 260.221 us; speedup vs baseline: 1.0787x; 1.0456x over previous
//
#include <hip/hip_runtime.h>

#define BATCH 16384

typedef float f2 __attribute__((ext_vector_type(2)));

// One block per segment b. 192 threads = 3 waves:
//   wave 0 : out0[b][0:64]  = sum_j table0[idx0[j]][:] * w0[j]  (weighted sum)
//            f2/lane, TWO rows per gather instr (lanes 0-31 row j, 32-63 row j+1),
//            512B per VMEM instr; cross-half shfl_xor(32) reduce at the end.
//   wave 1 : even rows of out1[b] = mean_j table1[idx1[j]][:]
//   wave 2 : odd  rows;  f2/lane covers the FULL 128-col row = 512B/instr.
//            wave2 partial -> LDS (512B), wave1 adds, scales by 1/cnt, stores.
//
// R5 post-mortem: idx/w scalarized (SGPR 48) but VGPR=16 showed no pipelining -
// the single v[8] bank drained to vmcnt(0) every block, avg ~3 loads in flight,
// HBM stuck at 31%. This version: (a) 512B per gather instr (2x bytes/vmcnt
// slot), (b) explicit prefetch of the NEXT block's idx/w between gather issue
// and FMA consume, (c) tail folded into one masked gather block (weight-0
// padding, clamped uniform idx) so no serial 1-load tail remains.
// In flight: 8 x 512B = 4KB/wave x ~30 waves/CU = 120KB >> 22KB Little's-law.
__global__ __launch_bounds__(192)
void combine_jagged_kernel(const float* __restrict__ table0,
                           const float* __restrict__ table1,
                           const float* __restrict__ w0,
                           const int* __restrict__ idx0,
                           const int* __restrict__ idx1,
                           const int* __restrict__ off0,
                           const int* __restrict__ off1,
                           float* __restrict__ out) {
    const int b    = blockIdx.x;
    const int wave = threadIdx.x >> 6;   // 0,1,2
    const int lane = threadIdx.x & 63;
    const int half = lane >> 5;          // 0: lanes 0-31, 1: lanes 32-63
    const int hl   = lane & 31;

    __shared__ f2 red[64];               // wave2 -> wave1 partial (128 floats)

    f2 acc = {0.0f, 0.0f};
    float inv = 0.0f;

    if (wave == 0) {
        const int s = __builtin_amdgcn_readfirstlane(off0[b]);
        const int e = __builtin_amdgcn_readfirstlane(off0[b + 1]);
        const float* tab = table0 + hl * 2;       // col pair (2*hl, 2*hl+1)
        int j = s;
        const int nfull = (e - s) >> 4;           // 16-row blocks
        if (nfull > 0) {
            int rr[16]; float ww[16];
            #pragma unroll
            for (int k = 0; k < 16; ++k) { rr[k] = idx0[j + k]; ww[k] = w0[j + k]; }
            for (int it = 0; it < nfull; ++it) {
                f2 v[8]; float wk[8];
                #pragma unroll
                for (int k = 0; k < 8; ++k) {
                    const int r = half ? rr[2 * k + 1] : rr[2 * k];
                    wk[k] = half ? ww[2 * k + 1] : ww[2 * k];
                    v[k] = *(const f2*)(tab + (size_t)r * 64);
                }
                j += 16;
                if (it + 1 < nfull) {             // prefetch under gather latency
                    #pragma unroll
                    for (int k = 0; k < 16; ++k) { rr[k] = idx0[j + k]; ww[k] = w0[j + k]; }
                }
                #pragma unroll
                for (int k = 0; k < 8; ++k) acc += v[k] * wk[k];
            }
        }
        const int rem = e - j;                    // 0..15 masked tail block
        if (rem > 0) {
            int rr[16]; float ww[16];
            #pragma unroll
            for (int k = 0; k < 16; ++k) {
                const int jk = j + (k < rem ? k : rem - 1);   // clamp: no OOB
                rr[k] = idx0[jk];
                ww[k] = (k < rem) ? w0[jk] : 0.0f;            // pad weight 0
            }
            f2 v[8]; float wk[8];
            #pragma unroll
            for (int k = 0; k < 8; ++k) {
                const int r = half ? rr[2 * k + 1] : rr[2 * k];
                wk[k] = half ? ww[2 * k + 1] : ww[2 * k];
                v[k] = *(const f2*)(tab + (size_t)r * 64);
            }
            #pragma unroll
            for (int k = 0; k < 8; ++k) acc += v[k] * wk[k];
        }
        // combine the two half-wave row-partials (same col pair in both halves)
        acc.x += __shfl_xor(acc.x, 32, 64);
        acc.y += __shfl_xor(acc.y, 32, 64);
    } else {
        const int s = __builtin_amdgcn_readfirstlane(off1[b]);
        const int e = __builtin_amdgcn_readfirstlane(off1[b + 1]);
        const int par = wave - 1;                 // row parity for this wave
        const float* tab = table1 + lane * 2;     // f2 col = (2*lane, 2*lane+1)
        int j = s;
        const int nfull = (e - s) >> 4;           // 16-row blocks (8 per wave)
        if (nfull > 0) {
            int rr[8];
            #pragma unroll
            for (int k = 0; k < 8; ++k) rr[k] = idx1[j + 2 * k + par];
            for (int it = 0; it < nfull; ++it) {
                f2 v[8];
                #pragma unroll
                for (int k = 0; k < 8; ++k) v[k] = *(const f2*)(tab + (size_t)rr[k] * 128);
                j += 16;
                if (it + 1 < nfull) {             // prefetch under gather latency
                    #pragma unroll
                    for (int k = 0; k < 8; ++k) rr[k] = idx1[j + 2 * k + par];
                }
                #pragma unroll
                for (int k = 0; k < 8; ++k) acc += v[k];
            }
        }
        const int rem = e - j;                    // masked tail block
        if (rem > 0) {
            int rr[8]; float mk[8];
            #pragma unroll
            for (int k = 0; k < 8; ++k) {
                const int o = 2 * k + par;
                const int jo = j + (o < rem ? o : rem - 1);   // clamp: no OOB
                rr[k] = idx1[jo];
                mk[k] = (o < rem) ? 1.0f : 0.0f;
            }
            f2 v[8];
            #pragma unroll
            for (int k = 0; k < 8; ++k) v[k] = *(const f2*)(tab + (size_t)rr[k] * 128);
            #pragma unroll
            for (int k = 0; k < 8; ++k) acc += v[k] * mk[k];
        }
        const int cnt = e - s;
        inv = (cnt > 0) ? 1.0f / (float)cnt : 0.0f;           // mean; empty -> 0
        if (wave == 2) red[lane] = acc;
    }

    __syncthreads();

    if (wave == 0) {
        if (half == 0) *(f2*)(out + (size_t)b * 64 + hl * 2) = acc;
    } else if (wave == 1) {
        acc += red[lane];
        acc *= inv;
        *(f2*)(out + (size_t)BATCH * 64 + (size_t)b * 128 + lane * 2) = acc;
    }
}

extern "C" void kernel_launch(void* const* d_in, const int* in_sizes, int n_in,
                              void* d_out, int out_size, void* d_ws, size_t ws_size,
                              hipStream_t stream) {
    const float* table0 = (const float*)d_in[0];   // [V, 64]
    const float* table1 = (const float*)d_in[1];   // [V, 128]
    const float* w0     = (const float*)d_in[2];   // [T]
    const int*   idx0   = (const int*)d_in[3];     // [T]
    const int*   idx1   = (const int*)d_in[4];     // [T]
    const int*   off0   = (const int*)d_in[5];     // [B+1]
    const int*   off1   = (const int*)d_in[6];     // [B+1]
    float* out = (float*)d_out;                    // [B*64] ++ [B*128]

    combine_jagged_kernel<<<BATCH, 192, 0, stream>>>(
        table0, table1, w0, idx0, idx1, off0, off1, out);
}